// Round 8
// baseline (458.014 us; speedup 1.0000x reference)
//
#include <hip/hip_runtime.h>
#include <cmath>

#define NB 16
#define NL 64
#define NP 512
#define NH 128
#define NG 10
#define ROWS (NB * NL * NP)          // 524288 rows

// output layout (flat float32, reference return order)
#define OFF_PI    ((size_t)0)
#define OFF_SIGMA ((size_t)5242880)
#define OFF_MU    ((size_t)10485760)
#define OFF_DIST  ((size_t)15728640)
#define OFF_MASK  ((size_t)16252928)

typedef __attribute__((ext_vector_type(8))) short short8;  // 8 bf16 = 4 VGPR
typedef __attribute__((ext_vector_type(4))) float f32x4;   // MFMA acc

// pack two f32 into one dword of two bf16 (round-nearest-even) -- R5-proven
__device__ __forceinline__ unsigned pk2(float a, float b) {
    unsigned ua = __float_as_uint(a);
    unsigned ub = __float_as_uint(b);
    ua = (ua + 0x7fffu + ((ua >> 16) & 1u)) >> 16;
    ub = (ub + 0x7fffu + ((ub >> 16) & 1u)) & 0xffff0000u;
    return ua | ub;
}

// ---------------------------------------------------------------------------
// Pack kernel: build the 8 KB bf16 B-fragment table in d_ws (R7-proven).
// Entry e = (ks*2+n)*64 + lane: col = n*16+(lane&15), k = ks*32+(lane>>4)*8+j.
// Cols: 0-9 pi | 10-19 sigma | 20-29 mu | 30,31 zero-pad.
// ---------------------------------------------------------------------------
__global__ __launch_bounds__(512) void k_pack(
    const float* __restrict__ Wpi, const float* __restrict__ Wsg,
    const float* __restrict__ Wmu, uint4* __restrict__ tbl)
{
    int e    = threadIdx.x;          // 512 entries
    int lane = e & 63;
    int n    = (e >> 6) & 1;
    int ks   = e >> 7;
    int lrow = lane & 15, lkg = lane >> 4;
    int col  = n * 16 + lrow;
    float w[8];
    #pragma unroll
    for (int j = 0; j < 8; ++j) {
        int k = ks * 32 + lkg * 8 + j;
        float v = 0.0f;
        if      (col < 10) v = Wpi[k * NG + col];
        else if (col < 20) v = Wsg[k * NG + col - 10];
        else if (col < 30) v = Wmu[k * NG + col - 20];
        w[j] = v;
    }
    uint4 u = {pk2(w[0], w[1]), pk2(w[2], w[3]),
               pk2(w[4], w[5]), pk2(w[6], w[7])};
    tbl[e] = u;
}

// ---------------------------------------------------------------------------
// Fused kernel: min-dist over 24 atoms + 3x GEMV [128 -> 30] via MFMA.
//
// R8: X reads COALESCED via LDS staging (R1/R5 comparison showed the
// per-lane 512B-stride float4 scatter is the common bottleneck of all
// fast variants). Tile [256 rows][32 k] with 16B-chunk XOR swizzle
//   position = chunk ^ (row & 7)   (applied on write AND read)
// -> staging writes, A-frag b128 reads, C-epilogue all bank-even.
// Register prefetch 1 stage ahead (32 VGPR across barriers, vs R6's 64
// that spilled); B-frags from an 8 KB LDS table (frees 32 VGPR);
// C-epilogue reuses the X buffer (wave-private slices, no barrier).
// LDS 41 KB, ~100 live VGPR -> 4 waves/SIMD.
// ---------------------------------------------------------------------------
__global__ __launch_bounds__(256, 4) void k_fused(
    const float* __restrict__ pos_l,   // [B, NL, 3]
    const float* __restrict__ pos_p,   // [B, NP, 24, 3]
    const int*   __restrict__ mask,    // [B, NL, NP] (bool as int32)
    const float* __restrict__ X,       // [ROWS, 128]
    const uint4* __restrict__ wtbl,    // [4][2][64] bf16 fragments (d_ws)
    const float* __restrict__ bpi,
    const float* __restrict__ bsg,
    const float* __restrict__ bmu,
    float* __restrict__ out_pi,
    float* __restrict__ out_sg,
    float* __restrict__ out_mu,
    float* __restrict__ dist_out,
    float* __restrict__ mask_out)
{
    __shared__ __align__(16) float xs[256 * 32];   // 32 KB X tile / C buffer
    __shared__ __align__(16) uint4 bt[512];        // 8 KB B-frag table

    const int tid  = threadIdx.x;
    const int wv   = tid >> 6;
    const int lane = tid & 63;
    const int lrow = lane & 15;              // A-row / C-col within tile
    const int lkg  = lane >> 4;              // k-group (8 k each)
    const int idx  = blockIdx.x * 256 + tid; // b*NL*NP + l*NP + p
    const size_t row0 = (size_t)blockIdx.x * 256;

    // staging geometry: inst j covers rows j*32 + wv*8 + a_, chunk b_
    const int a_ = lane >> 3;                // 0..7 (row-in-group, = row&7)
    const int b_ = lane & 7;                 // 16B chunk within 32-float slice
    const int wchunk = b_ ^ a_;              // swizzled LDS chunk position
    const int wro    = wv * 8 + a_;          // row offset (+ j*32)
    const float* gsb = X + (row0 + wro) * NH + b_ * 4;

    // ---- issue table + stage-0 X loads (latency hides under dist) ----
    uint4 bt0 = wtbl[tid];
    uint4 bt1 = wtbl[tid + 256];
    float4 pf[8];
    #pragma unroll
    for (int j = 0; j < 8; ++j)              // 8 lanes x 128B contiguous
        pf[j] = *(const float4*)(gsb + (size_t)j * 32 * NH);

    // bias for acc init (f32 exact)
    const int c0 = lrow, c1 = lrow + 16;
    const float bv0 = (c0 < 10) ? bpi[c0] : bsg[c0 - 10];
    const float bv1 = (c1 < 20) ? bsg[c1 - 10] : (c1 < 30 ? bmu[c1 - 20] : 0.0f);

    // ---------------- distance part (R5-verified) ----------------
    {
        int p  = idx & (NP - 1);
        int bl = idx >> 9;                   // b*NL + l
        int b  = bl >> 6;

        const float* xl = pos_l + bl * 3;
        float x0 = xl[0], x1 = xl[1], x2 = xl[2];
        float qs = x0 * x0 + x1 * x1 + x2 * x2;

        const float4* yp = (const float4*)(pos_p + ((size_t)(b * NP + p)) * 72);

        // d2<0 -> NaN -> 10000 in the ref: clamp to 1e8 (=10000^2 exactly),
        // one sqrt of the min at the end.
        float m2 = 1e30f;
        #pragma unroll
        for (int q = 0; q < 6; ++q) {
            float4 v0 = yp[q * 3 + 0];
            float4 v1 = yp[q * 3 + 1];
            float4 v2 = yp[q * 3 + 2];
            float c[12] = {v0.x, v0.y, v0.z, v0.w,
                           v1.x, v1.y, v1.z, v1.w,
                           v2.x, v2.y, v2.z, v2.w};
            #pragma unroll
            for (int a = 0; a < 4; ++a) {
                float yx = c[a * 3 + 0], yy = c[a * 3 + 1], yz = c[a * 3 + 2];
                float d2 = qs + (yx * yx + yy * yy + yz * yz)
                              - 2.0f * (x0 * yx + x1 * yy + x2 * yz);
                d2 = (d2 >= 0.0f) ? d2 : 1e8f;
                m2 = fminf(m2, d2);
            }
        }
        float m = sqrtf(m2);
        int mk = mask[idx];
        dist_out[idx] = mk ? m : 0.0f;
        mask_out[idx] = mk ? 1.0f : 0.0f;
    }

    // ---- commit table + stage 0 to LDS ----
    bt[tid]       = bt0;
    bt[tid + 256] = bt1;
    #pragma unroll
    for (int j = 0; j < 8; ++j)
        *(float4*)&xs[(wro + j * 32) * 32 + wchunk * 4] = pf[j];
    __syncthreads();

    // ---------------- MFMA GEMV over 4 K-stages ----------------
    f32x4 acc[4][2];
    #pragma unroll
    for (int m = 0; m < 4; ++m) {
        acc[m][0] = (f32x4){bv0, bv0, bv0, bv0};
        acc[m][1] = (f32x4){bv1, bv1, bv1, bv1};
    }

    const int s7 = lrow & 7;                 // (A-read row) & 7
    #pragma unroll
    for (int t = 0; t < 4; ++t) {
        if (t < 3) {                         // prefetch next stage (in regs)
            #pragma unroll
            for (int j = 0; j < 8; ++j)
                pf[j] = *(const float4*)(gsb + (size_t)j * 32 * NH
                                             + (t + 1) * 32);
        }
        short8 bf0 = __builtin_bit_cast(short8, bt[(t * 2 + 0) * 64 + lane]);
        short8 bf1 = __builtin_bit_cast(short8, bt[(t * 2 + 1) * 64 + lane]);

        #pragma unroll
        for (int m = 0; m < 4; ++m) {
            const int R = wv * 64 + m * 16 + lrow;    // R&7 == s7
            float4 lo = *(const float4*)&xs[R * 32 + ((2 * lkg)     ^ s7) * 4];
            float4 hi = *(const float4*)&xs[R * 32 + ((2 * lkg + 1) ^ s7) * 4];
            uint4 ua = {pk2(lo.x, lo.y), pk2(lo.z, lo.w),
                        pk2(hi.x, hi.y), pk2(hi.z, hi.w)};
            short8 af = __builtin_bit_cast(short8, ua);
            acc[m][0] = __builtin_amdgcn_mfma_f32_16x16x32_bf16(af, bf0, acc[m][0], 0, 0, 0);
            acc[m][1] = __builtin_amdgcn_mfma_f32_16x16x32_bf16(af, bf1, acc[m][1], 0, 0, 0);
        }

        if (t < 3) {
            __syncthreads();                 // all reads of stage t done
            #pragma unroll
            for (int j = 0; j < 8; ++j)
                *(float4*)&xs[(wro + j * 32) * 32 + wchunk * 4] = pf[j];
            __syncthreads();                 // stage t+1 visible
        }
    }

    // ---------------- C -> xs (wave-private slice, swizzled) -------------
    // C/D layout (m89/m91): col = lane&15, row = (lane>>4)*4 + reg.
    // Element (row Rabs, col c) -> chunk (c>>2) at pos (c>>2)^(Rabs&7).
    #pragma unroll
    for (int m = 0; m < 4; ++m)
        #pragma unroll
        for (int n = 0; n < 2; ++n)
            #pragma unroll
            for (int r = 0; r < 4; ++r) {
                int Rabs = wv * 64 + m * 16 + lkg * 4 + r;
                int ch   = n * 4 + (lrow >> 2);
                xs[Rabs * 32 + ((ch ^ (Rabs & 7)) * 4) + (lrow & 3)]
                    = acc[m][n][r];
            }

    // read own row (tid) back: chunk j at pos j^(tid&7). Same-wave only ->
    // compiler's lgkmcnt ordering suffices (R5-R7 proven pattern).
    float a[32];
    #pragma unroll
    for (int j = 0; j < 8; ++j)
        *(float4*)&a[4 * j] = *(const float4*)&xs[tid * 32 + ((j ^ (tid & 7)) * 4)];

    // ---------------- activations + stores ----------------
    const size_t ro = (size_t)idx * NG;

    // pi = softmax(a[0..9])
    float mx = a[0];
    #pragma unroll
    for (int g = 1; g < NG; ++g) mx = fmaxf(mx, a[g]);
    float e[NG], ssum = 0.0f;
    #pragma unroll
    for (int g = 0; g < NG; ++g) { e[g] = __expf(a[g] - mx); ssum += e[g]; }
    float inv = 1.0f / ssum;
    #pragma unroll
    for (int g = 0; g < 5; ++g)
        *(float2*)&out_pi[ro + 2 * g] = make_float2(e[2 * g] * inv,
                                                    e[2 * g + 1] * inv);

    // sigma = clip(leaky(a[10..19]) + 1.1, 1e-6, inf)
    #pragma unroll
    for (int g = 0; g < 5; ++g) {
        float xa = a[10 + 2 * g], xb = a[10 + 2 * g + 1];
        float va = fmaxf((xa >= 0.0f ? xa : 0.01f * xa) + 1.1f, 1e-6f);
        float vb = fmaxf((xb >= 0.0f ? xb : 0.01f * xb) + 1.1f, 1e-6f);
        *(float2*)&out_sg[ro + 2 * g] = make_float2(va, vb);
    }

    // mu = leaky(a[20..29]) + 1.0
    #pragma unroll
    for (int g = 0; g < 5; ++g) {
        float xa = a[20 + 2 * g], xb = a[20 + 2 * g + 1];
        float va = (xa >= 0.0f ? xa : 0.01f * xa) + 1.0f;
        float vb = (xb >= 0.0f ? xb : 0.01f * xb) + 1.0f;
        *(float2*)&out_mu[ro + 2 * g] = make_float2(va, vb);
    }
}

// ---------------------------------------------------------------------------
extern "C" void kernel_launch(void* const* d_in, const int* in_sizes, int n_in,
                              void* d_out, int out_size, void* d_ws, size_t ws_size,
                              hipStream_t stream) {
    const float* pos_l    = (const float*)d_in[0];
    const float* pos_p    = (const float*)d_in[1];
    const float* Interact = (const float*)d_in[2];
    const int*   mask     = (const int*)  d_in[3];
    const float* Wpi      = (const float*)d_in[4];
    const float* bpi      = (const float*)d_in[5];
    const float* Wsg      = (const float*)d_in[6];
    const float* bsg      = (const float*)d_in[7];
    const float* Wmu      = (const float*)d_in[8];
    const float* bmu      = (const float*)d_in[9];

    float* out      = (float*)d_out;
    float* out_pi   = out + OFF_PI;
    float* out_sg   = out + OFF_SIGMA;
    float* out_mu   = out + OFF_MU;
    float* out_dist = out + OFF_DIST;
    float* out_mask = out + OFF_MASK;

    uint4* wtbl = (uint4*)d_ws;              // 8 KB fragment table

    hipLaunchKernelGGL(k_pack, dim3(1), dim3(512), 0, stream,
                       Wpi, Wsg, Wmu, wtbl);
    hipLaunchKernelGGL(k_fused, dim3(ROWS / 256), dim3(256), 0, stream,
                       pos_l, pos_p, mask, Interact, wtbl,
                       bpi, bsg, bmu,
                       out_pi, out_sg, out_mu, out_dist, out_mask);
}

// Round 9
// 431.998 us; speedup vs baseline: 1.0602x; 1.0602x over previous
//
#include <hip/hip_runtime.h>
#include <cmath>

#define NB 16
#define NL 64
#define NP 512
#define NH 128
#define NG 10
#define ROWS (NB * NL * NP)          // 524288 rows

// output layout (flat float32, reference return order)
#define OFF_PI    ((size_t)0)
#define OFF_SIGMA ((size_t)5242880)
#define OFF_MU    ((size_t)10485760)
#define OFF_DIST  ((size_t)15728640)
#define OFF_MASK  ((size_t)16252928)

typedef __attribute__((ext_vector_type(8))) short short8;  // 8 bf16 = 4 VGPR
typedef __attribute__((ext_vector_type(4))) float f32x4;   // MFMA acc

// pack two f32 into one dword of two bf16 (round-nearest-even) -- R5-proven
__device__ __forceinline__ unsigned pk2(float a, float b) {
    unsigned ua = __float_as_uint(a);
    unsigned ub = __float_as_uint(b);
    ua = (ua + 0x7fffu + ((ua >> 16) & 1u)) >> 16;
    ub = (ub + 0x7fffu + ((ub >> 16) & 1u)) & 0xffff0000u;
    return ua | ub;
}

// ---------------------------------------------------------------------------
// Pack kernel (R7-proven): 8 KB bf16 B-fragment table in d_ws.
// Entry e = (ks*2+n)*64 + lane: col = n*16+(lane&15), k = ks*32+(lane>>4)*8+j.
// Cols: 0-9 pi | 10-19 sigma | 20-29 mu | 30,31 zero-pad.
// ---------------------------------------------------------------------------
__global__ __launch_bounds__(512) void k_pack(
    const float* __restrict__ Wpi, const float* __restrict__ Wsg,
    const float* __restrict__ Wmu, uint4* __restrict__ tbl)
{
    int e    = threadIdx.x;          // 512 entries
    int lane = e & 63;
    int n    = (e >> 6) & 1;
    int ks   = e >> 7;
    int lrow = lane & 15, lkg = lane >> 4;
    int col  = n * 16 + lrow;
    float w[8];
    #pragma unroll
    for (int j = 0; j < 8; ++j) {
        int k = ks * 32 + lkg * 8 + j;
        float v = 0.0f;
        if      (col < 10) v = Wpi[k * NG + col];
        else if (col < 20) v = Wsg[k * NG + col - 10];
        else if (col < 30) v = Wmu[k * NG + col - 20];
        w[j] = v;
    }
    uint4 u = {pk2(w[0], w[1]), pk2(w[2], w[3]),
               pk2(w[4], w[5]), pk2(w[6], w[7])};
    tbl[e] = u;
}

// ---------------------------------------------------------------------------
// Fused kernel: min-dist over 24 atoms + 3x GEMV [128 -> 30] via MFMA.
//
// R9: X staged via LDS as BF16, one 64-k stage at a time (32 KB single
// buffer). Coalesced cooperative loads replace R5's 2048 scattered
// lane-requests/wave on X (TCP address-path relief -- the revised
// bottleneck model); bf16 conversion happens at staging (off the MFMA
// path); cross-barrier state is 32 VGPR of pre-packed uint2 (spill-safe).
// Only 3 barriers; stage-1 loads fly over stage-0 MFMAs; stage-0 loads
// over dist. LDS layout: row r (128 B of bf16), 16B chunk C stored at
// position C ^ (r&7)  -> staging b64 writes bank-even, A-frag b128 reads
// conflict-free. LDS reads are wave-banded -> barrier-free C epilogue
// (R8-verified code reused).
// ---------------------------------------------------------------------------
__global__ __launch_bounds__(256, 4) void k_fused(
    const float* __restrict__ pos_l,   // [B, NL, 3]
    const float* __restrict__ pos_p,   // [B, NP, 24, 3]
    const int*   __restrict__ mask,    // [B, NL, NP] (bool as int32)
    const float* __restrict__ X,       // [ROWS, 128]
    const uint4* __restrict__ wtbl,    // [4][2][64] bf16 fragments (d_ws)
    const float* __restrict__ bpi,
    const float* __restrict__ bsg,
    const float* __restrict__ bmu,
    float* __restrict__ out_pi,
    float* __restrict__ out_sg,
    float* __restrict__ out_mu,
    float* __restrict__ dist_out,
    float* __restrict__ mask_out)
{
    __shared__ __align__(16) char smem[32768];   // bf16 X stage / f32 C buffer
    float* cs = (float*)smem;

    const int tid  = threadIdx.x;
    const int wv   = tid >> 6;
    const int lane = tid & 63;
    const int lrow = lane & 15;              // A-row / C-col within tile
    const int lkg  = lane >> 4;              // k-group (8 k each)
    const int idx  = blockIdx.x * 256 + tid; // b*NL*NP + l*NP + p
    const size_t row0 = (size_t)blockIdx.x * 256;

    // staging: slot s=j*256+tid -> row j*16 + (tid>>4), f32-chunk tid&15
    const int r0 = tid >> 4, c0 = tid & 15;
    const float* gs = X + (row0 + r0) * NH + c0 * 4;
    // bf16 dest byte for (row r, f32-chunk c): r*128 + ((c>>1 ^ (r&7))*16)
    // + (c&1)*8 ; r&7 == r0&7 for all j
    const int wbyte0 = r0 * 128 + ((((c0 >> 1) ^ (r0 & 7)) * 16) | ((c0 & 1) * 8));

    // ---- issue stage-0 X loads (fly during dist) ----
    float4 pf[16];
    #pragma unroll
    for (int j = 0; j < 16; ++j)
        pf[j] = *(const float4*)(gs + (size_t)j * 16 * NH);

    // bias for acc init (f32 exact)
    const int cc0 = lrow, cc1 = lrow + 16;
    const float bv0 = (cc0 < 10) ? bpi[cc0] : bsg[cc0 - 10];
    const float bv1 = (cc1 < 20) ? bsg[cc1 - 10] : (cc1 < 30 ? bmu[cc1 - 20] : 0.0f);

    // ---------------- distance part (R5-verified) ----------------
    {
        int p  = idx & (NP - 1);
        int bl = idx >> 9;                   // b*NL + l
        int b  = bl >> 6;

        const float* xl = pos_l + bl * 3;
        float x0 = xl[0], x1 = xl[1], x2 = xl[2];
        float qs = x0 * x0 + x1 * x1 + x2 * x2;

        const float4* yp = (const float4*)(pos_p + ((size_t)(b * NP + p)) * 72);

        // d2<0 -> NaN -> 10000 in the ref: clamp to 1e8 (=10000^2 exactly),
        // one sqrt of the min at the end.
        float m2 = 1e30f;
        #pragma unroll
        for (int q = 0; q < 6; ++q) {
            float4 v0 = yp[q * 3 + 0];
            float4 v1 = yp[q * 3 + 1];
            float4 v2 = yp[q * 3 + 2];
            float c[12] = {v0.x, v0.y, v0.z, v0.w,
                           v1.x, v1.y, v1.z, v1.w,
                           v2.x, v2.y, v2.z, v2.w};
            #pragma unroll
            for (int a = 0; a < 4; ++a) {
                float yx = c[a * 3 + 0], yy = c[a * 3 + 1], yz = c[a * 3 + 2];
                float d2 = qs + (yx * yx + yy * yy + yz * yz)
                              - 2.0f * (x0 * yx + x1 * yy + x2 * yz);
                d2 = (d2 >= 0.0f) ? d2 : 1e8f;
                m2 = fminf(m2, d2);
            }
        }
        float m = sqrtf(m2);
        int mk = mask[idx];
        dist_out[idx] = mk ? m : 0.0f;
        mask_out[idx] = mk ? 1.0f : 0.0f;
    }

    // ---- convert + commit stage 0 (pf dies here; 32 VGPR of pc live) ----
    {
        uint2 pc[16];
        #pragma unroll
        for (int j = 0; j < 16; ++j)
            pc[j] = make_uint2(pk2(pf[j].x, pf[j].y), pk2(pf[j].z, pf[j].w));
        #pragma unroll
        for (int j = 0; j < 16; ++j)
            *(uint2*)(smem + wbyte0 + j * 2048) = pc[j];
    }
    __syncthreads();                         // B1: stage 0 visible

    // ---------------- MFMA GEMV ----------------
    f32x4 acc[4][2];
    #pragma unroll
    for (int m = 0; m < 4; ++m) {
        acc[m][0] = (f32x4){bv0, bv0, bv0, bv0};
        acc[m][1] = (f32x4){bv1, bv1, bv1, bv1};
    }

    const int s7 = lrow & 7;                 // (A-read row) & 7
    const char* abase = smem + wv * 8192 + lrow * 128;

    // one 32-k MFMA step: global k-step ksg, stage-local chunk base Cb
#define DO_KS(ksg, Cb)                                                        \
    {                                                                         \
        short8 bf0 = __builtin_bit_cast(short8, wtbl[((ksg) * 2 + 0) * 64 + lane]); \
        short8 bf1 = __builtin_bit_cast(short8, wtbl[((ksg) * 2 + 1) * 64 + lane]); \
        _Pragma("unroll")                                                     \
        for (int m = 0; m < 4; ++m) {                                         \
            short8 af = *(const short8*)(abase + m * 2048                     \
                                         + ((((Cb)) ^ s7) * 16));             \
            acc[m][0] = __builtin_amdgcn_mfma_f32_16x16x32_bf16(af, bf0, acc[m][0], 0, 0, 0); \
            acc[m][1] = __builtin_amdgcn_mfma_f32_16x16x32_bf16(af, bf1, acc[m][1], 0, 0, 0); \
        }                                                                     \
    }

    // stage 0, first 32-k step
    DO_KS(0, lkg)

    // issue stage-1 X loads (fly over remaining stage-0 MFMAs)
    #pragma unroll
    for (int j = 0; j < 16; ++j)
        pf[j] = *(const float4*)(gs + (size_t)j * 16 * NH + 64);

    // stage 0, second 32-k step
    DO_KS(1, 4 + lkg)

    // convert stage 1 early (pf dies; pc 32 VGPR across B2)
    uint2 pc[16];
    #pragma unroll
    for (int j = 0; j < 16; ++j)
        pc[j] = make_uint2(pk2(pf[j].x, pf[j].y), pk2(pf[j].z, pf[j].w));

    __syncthreads();                         // B2: all stage-0 reads done
    #pragma unroll
    for (int j = 0; j < 16; ++j)
        *(uint2*)(smem + wbyte0 + j * 2048) = pc[j];
    __syncthreads();                         // B3: stage 1 visible

    DO_KS(2, lkg)
    DO_KS(3, 4 + lkg)
#undef DO_KS

    // ---------------- C -> LDS epilogue (R8-verified, wave-banded) -------
    // C/D layout (m89/m91): col = lane&15, row = (lane>>4)*4 + reg.
    // All LDS reads below are wave-banded -> no barrier needed (each wave
    // reads/writes only rows [wv*64, wv*64+64), and stage-1 A-reads of this
    // band were by this wave alone).
    #pragma unroll
    for (int m = 0; m < 4; ++m)
        #pragma unroll
        for (int n = 0; n < 2; ++n)
            #pragma unroll
            for (int r = 0; r < 4; ++r) {
                int Rabs = wv * 64 + m * 16 + lkg * 4 + r;
                int ch   = n * 4 + (lrow >> 2);
                cs[Rabs * 32 + ((ch ^ (Rabs & 7)) * 4) + (lrow & 3)]
                    = acc[m][n][r];
            }

    float a[32];
    #pragma unroll
    for (int j = 0; j < 8; ++j)
        *(float4*)&a[4 * j] = *(const float4*)&cs[tid * 32 + ((j ^ (tid & 7)) * 4)];

    // ---------------- activations + stores ----------------
    const size_t ro = (size_t)idx * NG;

    // pi = softmax(a[0..9])
    float mx = a[0];
    #pragma unroll
    for (int g = 1; g < NG; ++g) mx = fmaxf(mx, a[g]);
    float e[NG], ssum = 0.0f;
    #pragma unroll
    for (int g = 0; g < NG; ++g) { e[g] = __expf(a[g] - mx); ssum += e[g]; }
    float inv = 1.0f / ssum;
    #pragma unroll
    for (int g = 0; g < 5; ++g)
        *(float2*)&out_pi[ro + 2 * g] = make_float2(e[2 * g] * inv,
                                                    e[2 * g + 1] * inv);

    // sigma = clip(leaky(a[10..19]) + 1.1, 1e-6, inf)
    #pragma unroll
    for (int g = 0; g < 5; ++g) {
        float xa = a[10 + 2 * g], xb = a[10 + 2 * g + 1];
        float va = fmaxf((xa >= 0.0f ? xa : 0.01f * xa) + 1.1f, 1e-6f);
        float vb = fmaxf((xb >= 0.0f ? xb : 0.01f * xb) + 1.1f, 1e-6f);
        *(float2*)&out_sg[ro + 2 * g] = make_float2(va, vb);
    }

    // mu = leaky(a[20..29]) + 1.0
    #pragma unroll
    for (int g = 0; g < 5; ++g) {
        float xa = a[20 + 2 * g], xb = a[20 + 2 * g + 1];
        float va = (xa >= 0.0f ? xa : 0.01f * xa) + 1.0f;
        float vb = (xb >= 0.0f ? xb : 0.01f * xb) + 1.0f;
        *(float2*)&out_mu[ro + 2 * g] = make_float2(va, vb);
    }
}

// ---------------------------------------------------------------------------
extern "C" void kernel_launch(void* const* d_in, const int* in_sizes, int n_in,
                              void* d_out, int out_size, void* d_ws, size_t ws_size,
                              hipStream_t stream) {
    const float* pos_l    = (const float*)d_in[0];
    const float* pos_p    = (const float*)d_in[1];
    const float* Interact = (const float*)d_in[2];
    const int*   mask     = (const int*)  d_in[3];
    const float* Wpi      = (const float*)d_in[4];
    const float* bpi      = (const float*)d_in[5];
    const float* Wsg      = (const float*)d_in[6];
    const float* bsg      = (const float*)d_in[7];
    const float* Wmu      = (const float*)d_in[8];
    const float* bmu      = (const float*)d_in[9];

    float* out      = (float*)d_out;
    float* out_pi   = out + OFF_PI;
    float* out_sg   = out + OFF_SIGMA;
    float* out_mu   = out + OFF_MU;
    float* out_dist = out + OFF_DIST;
    float* out_mask = out + OFF_MASK;

    uint4* wtbl = (uint4*)d_ws;              // 8 KB fragment table

    hipLaunchKernelGGL(k_pack, dim3(1), dim3(512), 0, stream,
                       Wpi, Wsg, Wmu, wtbl);
    hipLaunchKernelGGL(k_fused, dim3(ROWS / 256), dim3(256), 0, stream,
                       pos_l, pos_p, mask, Interact, wtbl,
                       bpi, bsg, bmu,
                       out_pi, out_sg, out_mu, out_dist, out_mask);
}